// Round 1
// baseline (637.116 us; speedup 1.0000x reference)
//
#include <hip/hip_runtime.h>
#include <hip/hip_bf16.h>
#include <stdint.h>

// ---------- types ----------
typedef __attribute__((ext_vector_type(8))) short     bf16x8;  // MFMA A/B frag (4 VGPR)
typedef __attribute__((ext_vector_type(4))) float     f32x4;   // MFMA C/D frag
typedef __attribute__((ext_vector_type(8))) unsigned short u16x8;

__device__ __forceinline__ unsigned short f2bf(float f) {
  unsigned int u = __float_as_uint(f);
  u += 0x7FFFu + ((u >> 16) & 1u);   // round-to-nearest-even
  return (unsigned short)(u >> 16);
}
__device__ __forceinline__ float bf2f(unsigned short s) {
  return __uint_as_float(((unsigned int)s) << 16);
}

__device__ __forceinline__ void async_cp16(const void* g, void* l) {
  __builtin_amdgcn_global_load_lds((const __attribute__((address_space(1))) void*)g,
                                   (__attribute__((address_space(3))) void*)l,
                                   16, 0, 0);
}

// ---------- fp32 -> bf16 conversion (memory-bound, vectorized) ----------
__global__ __launch_bounds__(256) void cvt_f32_to_bf16(const float* __restrict__ in,
                                                       unsigned short* __restrict__ out,
                                                       int n4) {
  int i = blockIdx.x * blockDim.x + threadIdx.x;
  const int stride = gridDim.x * blockDim.x;
  for (; i < n4; i += stride) {
    const float4 v = ((const float4*)in)[i];
    ushort4 o;
    o.x = f2bf(v.x); o.y = f2bf(v.y); o.z = f2bf(v.z); o.w = f2bf(v.w);
    ((ushort4*)out)[i] = o;
  }
}

// ---------- SwiGLU: h[m,e] = silu(ug[m,e]) * ug[m,e+E] ----------
__global__ __launch_bounds__(256) void swiglu_k(const unsigned short* __restrict__ ug,
                                                unsigned short* __restrict__ h,
                                                int total8) {
  int i = blockIdx.x * blockDim.x + threadIdx.x;
  const int stride = gridDim.x * blockDim.x;
  for (; i < total8; i += stride) {
    const int m = i >> 8;           // E/8 = 256 chunks per row
    const int e = (i & 255) << 3;
    const u16x8 g = *(const u16x8*)(ug + (size_t)m * 4096 + e);
    const u16x8 u = *(const u16x8*)(ug + (size_t)m * 4096 + 2048 + e);
    u16x8 o;
#pragma unroll
    for (int j = 0; j < 8; ++j) {
      const float gv = bf2f((unsigned short)g[j]);
      const float uv = bf2f((unsigned short)u[j]);
      const float s  = gv / (1.0f + __expf(-gv));
      o[j] = f2bf(s * uv);
    }
    *(u16x8*)(h + (size_t)m * 2048 + e) = o;
  }
}

// ---------- NT bf16 GEMM: C[m,n] = sum_k A[m,k]*B[n,k] ----------
// 128x128 tile, BK=32, 256 threads = 4 waves (2x2), each wave 64x64 = 4x4 MFMA frags.
// m97 structure: global_load_lds width-16 staging, 2 barriers per K-step.
template <bool OUT_BF16>
__global__ __launch_bounds__(256) void gemm_nt(const unsigned short* __restrict__ A,
                                               const unsigned short* __restrict__ B,
                                               void* __restrict__ Cv,
                                               int M, int N, int K) {
  __shared__ unsigned short As[128 * 32];
  __shared__ unsigned short Bs[128 * 32];

  const int tid  = threadIdx.x;
  const int wave = tid >> 6;
  const int lane = tid & 63;
  const int wr   = wave >> 1;       // wave row 0..1
  const int wc   = wave & 1;        // wave col 0..1
  const int row0 = blockIdx.y * 128;
  const int col0 = blockIdx.x * 128;
  const size_t Kb = (size_t)K * 2;  // bytes per row

  // staging: tile is 128 rows x 64 bytes (8 KiB); each wave covers 2 KiB,
  // linear LDS dest = wave-uniform base + lane*16 (global_load_lds constraint)
  const int sOff0 = wave * 2048 + lane * 16;
  const int sOff1 = sOff0 + 1024;
  const int r0s = sOff0 >> 6, c0s = sOff0 & 63;
  const int r1s = sOff1 >> 6, c1s = sOff1 & 63;

  const char* gA0 = (const char*)A + (size_t)(row0 + r0s) * Kb + c0s;
  const char* gA1 = (const char*)A + (size_t)(row0 + r1s) * Kb + c1s;
  const char* gB0 = (const char*)B + (size_t)(col0 + r0s) * Kb + c0s;
  const char* gB1 = (const char*)B + (size_t)(col0 + r1s) * Kb + c1s;
  char* lA0 = (char*)As + sOff0;
  char* lA1 = (char*)As + sOff1;
  char* lB0 = (char*)Bs + sOff0;
  char* lB1 = (char*)Bs + sOff1;

  // fragment read addresses: lane l reads row (l&15), k-group (l>>4)*8 elems
  const int fr = lane & 15, fg = lane >> 4;
  const unsigned short* aP = As + (wr * 64 + fr) * 32 + fg * 8;
  const unsigned short* bP = Bs + (wc * 64 + fr) * 32 + fg * 8;

  f32x4 acc[4][4];
#pragma unroll
  for (int m = 0; m < 4; ++m)
#pragma unroll
    for (int n = 0; n < 4; ++n) acc[m][n] = (f32x4){0.f, 0.f, 0.f, 0.f};

  const int nk = K >> 5;
  for (int kt = 0; kt < nk; ++kt) {
    async_cp16(gA0, lA0); async_cp16(gA1, lA1);
    async_cp16(gB0, lB0); async_cp16(gB1, lB1);
    __syncthreads();   // drains vmcnt -> tile resident

    bf16x8 af[4], bfr[4];
#pragma unroll
    for (int m = 0; m < 4; ++m) af[m] = *(const bf16x8*)(aP + m * 16 * 32);
#pragma unroll
    for (int n = 0; n < 4; ++n) bfr[n] = *(const bf16x8*)(bP + n * 16 * 32);
#pragma unroll
    for (int m = 0; m < 4; ++m)
#pragma unroll
      for (int n = 0; n < 4; ++n)
        acc[m][n] = __builtin_amdgcn_mfma_f32_16x16x32_bf16(af[m], bfr[n], acc[m][n], 0, 0, 0);

    __syncthreads();   // all reads done before next stage overwrites
    gA0 += 64; gA1 += 64; gB0 += 64; gB1 += 64;
  }

  // C/D frag layout (m89-verified): col = lane&15, row = (lane>>4)*4 + i
  const int rowbase = row0 + wr * 64 + fg * 4;
  const int colbase = col0 + wc * 64 + fr;
  if (OUT_BF16) {
    unsigned short* Cp = (unsigned short*)Cv;
#pragma unroll
    for (int m = 0; m < 4; ++m)
#pragma unroll
      for (int n = 0; n < 4; ++n)
#pragma unroll
        for (int i = 0; i < 4; ++i)
          Cp[(size_t)(rowbase + m * 16 + i) * N + (colbase + n * 16)] = f2bf(acc[m][n][i]);
  } else {
    float* Cp = (float*)Cv;
#pragma unroll
    for (int m = 0; m < 4; ++m)
#pragma unroll
      for (int n = 0; n < 4; ++n)
#pragma unroll
        for (int i = 0; i < 4; ++i)
          Cp[(size_t)(rowbase + m * 16 + i) * N + (colbase + n * 16)] = acc[m][n][i];
  }
}

// ---------- launch ----------
extern "C" void kernel_launch(void* const* d_in, const int* in_sizes, int n_in,
                              void* d_out, int out_size, void* d_ws, size_t ws_size,
                              hipStream_t stream) {
  const int M = 4096, K = 7168, E = 2048;

  const float* x   = (const float*)d_in[0];  // [M,K]
  const float* wug = (const float*)d_in[1];  // [2E,K]
  const float* wd  = (const float*)d_in[2];  // [K,E]
  float* out = (float*)d_out;                // [M,K]

  // workspace layout (bytes)
  char* ws = (char*)d_ws;
  unsigned short* xb  = (unsigned short*)(ws);               //  58,720,256
  unsigned short* wub = (unsigned short*)(ws + 58720256);    //  58,720,256
  unsigned short* wdb = (unsigned short*)(ws + 117440512);   //  29,360,128
  unsigned short* ug  = (unsigned short*)(ws + 146800640);   //  33,554,432
  unsigned short* h   = (unsigned short*)(ws + 180355072);   //  16,777,216
  if (ws_size < 197132288) return;                           // need ~188 MiB

  // 1) cast inputs to bf16
  cvt_f32_to_bf16<<<2048, 256, 0, stream>>>(x,   xb,  M * K / 4);
  cvt_f32_to_bf16<<<2048, 256, 0, stream>>>(wug, wub, 2 * E * K / 4);
  cvt_f32_to_bf16<<<1024, 256, 0, stream>>>(wd,  wdb, K * E / 4);

  // 2) ug = x @ w_up_gate^T   [4096, 4096] bf16
  gemm_nt<true><<<dim3(4096 / 128, 4096 / 128), 256, 0, stream>>>(xb, wub, ug, M, 2 * E, K);

  // 3) h = silu(gate) * up    [4096, 2048] bf16
  swiglu_k<<<2048, 256, 0, stream>>>(ug, h, M * E / 8);

  // 4) out = h @ w_down^T     [4096, 7168] fp32
  gemm_nt<false><<<dim3(7168 / 128, 4096 / 128), 256, 0, stream>>>(h, wdb, out, M, K, E);
}

// Round 2
// 407.401 us; speedup vs baseline: 1.5639x; 1.5639x over previous
//
#include <hip/hip_runtime.h>
#include <hip/hip_bf16.h>
#include <stdint.h>

// ---------- types ----------
typedef __attribute__((ext_vector_type(8))) short     bf16x8;  // MFMA A/B frag (4 VGPR)
typedef __attribute__((ext_vector_type(4))) float     f32x4;   // MFMA C/D frag
typedef __attribute__((ext_vector_type(8))) unsigned short u16x8;

__device__ __forceinline__ unsigned short f2bf(float f) {
  unsigned int u = __float_as_uint(f);
  u += 0x7FFFu + ((u >> 16) & 1u);   // round-to-nearest-even
  return (unsigned short)(u >> 16);
}
__device__ __forceinline__ float bf2f(unsigned short s) {
  return __uint_as_float(((unsigned int)s) << 16);
}

__device__ __forceinline__ void async_cp16(const void* g, void* l) {
  __builtin_amdgcn_global_load_lds((const __attribute__((address_space(1))) void*)g,
                                   (__attribute__((address_space(3))) void*)l,
                                   16, 0, 0);
}

// ---------- fp32 -> bf16 conversion (memory-bound, vectorized) ----------
__global__ __launch_bounds__(256) void cvt_f32_to_bf16(const float* __restrict__ in,
                                                       unsigned short* __restrict__ out,
                                                       int n4) {
  int i = blockIdx.x * blockDim.x + threadIdx.x;
  const int stride = gridDim.x * blockDim.x;
  for (; i < n4; i += stride) {
    const float4 v = ((const float4*)in)[i];
    ushort4 o;
    o.x = f2bf(v.x); o.y = f2bf(v.y); o.z = f2bf(v.z); o.w = f2bf(v.w);
    ((ushort4*)out)[i] = o;
  }
}

// ---------- SwiGLU: h[m,e] = silu(ug[m,e]) * ug[m,e+E] ----------
__global__ __launch_bounds__(256) void swiglu_k(const unsigned short* __restrict__ ug,
                                                unsigned short* __restrict__ h,
                                                int total8) {
  int i = blockIdx.x * blockDim.x + threadIdx.x;
  const int stride = gridDim.x * blockDim.x;
  for (; i < total8; i += stride) {
    const int m = i >> 8;           // E/8 = 256 chunks per row
    const int e = (i & 255) << 3;
    const u16x8 g = *(const u16x8*)(ug + (size_t)m * 4096 + e);
    const u16x8 u = *(const u16x8*)(ug + (size_t)m * 4096 + 2048 + e);
    u16x8 o;
#pragma unroll
    for (int j = 0; j < 8; ++j) {
      const float gv = bf2f((unsigned short)g[j]);
      const float uv = bf2f((unsigned short)u[j]);
      const float s  = gv / (1.0f + __expf(-gv));
      o[j] = f2bf(s * uv);
    }
    *(u16x8*)(h + (size_t)m * 2048 + e) = o;
  }
}

// ---------- 256x256 deep-pipelined NT bf16 GEMM ----------
// C[m,n] = sum_k A[m,k]*B[n,k].  512 threads = 8 waves (2Mx4N), wave = 128x64 out.
// LDS: 4-slot ring at kstep (32-elem) granularity: slot = 16KB A + 16KB B = 128KiB.
// Per kstep h: 2 phases x 16 MFMA; stage kstep h+3 (2 gload_lds per phase);
// ONE counted vmcnt(8) per kstep (never 0) + raw s_barrier.
// LDS line L (128B) holds rows 2L,2L+1; 16B-slot swizzle p = (parity*4+fg) ^ (L&7):
// read side 2-way conflict (free); staging pre-swizzles the per-lane GLOBAL source.
template <int K, int N, bool OUT_BF16>
__global__ __launch_bounds__(512, 2) void gemm_nt(const unsigned short* __restrict__ A,
                                                  const unsigned short* __restrict__ B,
                                                  void* __restrict__ Cv) {
  extern __shared__ char sm[];   // 131072 bytes: [4 slots x 16KB A][4 slots x 16KB B]
  constexpr int nbx = N / 256;
  constexpr int nwg = (4096 / 256) * nbx;
  constexpr size_t K2 = (size_t)K * 2;

  // T1: bijective XCD swizzle (nwg % 8 == 0 for both GEMMs)
  const int bid = blockIdx.x;
  constexpr int q8 = nwg / 8;
  const int swz = (bid & 7) * q8 + (bid >> 3);
  const int bx = swz % nbx, by = swz / nbx;
  const int row0 = by * 256, col0 = bx * 256;

  const int tid = threadIdx.x, wave = tid >> 6, lane = tid & 63;
  const int wr = wave >> 2, wc = wave & 3;       // wave 2x4 grid
  const int fr = lane & 15, fg = lane >> 4;      // fragment row / k-group

  // ---- staging addresses (pre-swizzled global source, linear LDS dest) ----
  const int l3 = lane >> 3;                 // 0..7
  const int q  = (lane & 7) ^ l3;           // 0..7 involution
  const int qr = q >> 2;                    // row parity
  const int qc = (q & 3) * 16;              // byte offset within kstep's 64B row
  const char* gA[2]; const char* gB[2];
#pragma unroll
  for (int i = 0; i < 2; ++i) {
    const int L = i * 64 + wave * 8 + l3;   // LDS line 0..127
    gA[i] = (const char*)A + (size_t)(row0 + 2 * L + qr) * K2 + qc;
    gB[i] = (const char*)B + (size_t)(col0 + 2 * L + qr) * K2 + qc;
  }

  // ---- fragment read offsets (swizzled) ----
  const int rbA = wr * 128 + fr;
  const int offA0 = (rbA >> 1) * 128 + (((((rbA & 1) << 2) | fg) ^ ((rbA >> 1) & 7)) << 4);
  const int rbB = wc * 64 + fr;
  const int offB0 = (rbB >> 1) * 128 + (((((rbB & 1) << 2) | fg) ^ ((rbB >> 1) & 7)) << 4);

  f32x4 acc[8][4];
#pragma unroll
  for (int m = 0; m < 8; ++m)
#pragma unroll
    for (int n = 0; n < 4; ++n) acc[m][n] = (f32x4){0.f, 0.f, 0.f, 0.f};

  constexpr int nh = K / 32;    // ksteps

#define STAGE_A(h, slot) do {                                   \
    char* d_ = sm + (slot) * 16384 + wave * 1024;               \
    async_cp16(gA[0] + (size_t)(h) * 64, d_);                   \
    async_cp16(gA[1] + (size_t)(h) * 64, d_ + 8192);            \
  } while (0)
#define STAGE_B(h, slot) do {                                   \
    char* d_ = sm + 65536 + (slot) * 16384 + wave * 1024;       \
    async_cp16(gB[0] + (size_t)(h) * 64, d_);                   \
    async_cp16(gB[1] + (size_t)(h) * 64, d_ + 8192);            \
  } while (0)

  // prologue: stage ksteps 0,1,2 (12 loads in flight)
#pragma unroll
  for (int hp = 0; hp < 3; ++hp) { STAGE_A(hp, hp); STAGE_B(hp, hp); }

  for (int h = 0; h < nh; ++h) {
    const int slot = h & 3;
    // T4: counted wait — drains ONLY kstep h's 4 loads, leaves h+1/h+2 in flight
    asm volatile("s_waitcnt vmcnt(8)" ::: "memory");
    __builtin_amdgcn_s_barrier();

    const char* aBase = sm + slot * 16384;
    const char* bBase = sm + 65536 + slot * 16384;
    const int hs = (h + 3 < nh) ? h + 3 : nh - 1;   // clamped tail keeps vmcnt discipline
    const int sslot = (h + 3) & 3;                  // freed at end of kstep h-1

    bf16x8 af[4], bfr[4];
    // ---- phase 0: m-half 0 ----
#pragma unroll
    for (int n = 0; n < 4; ++n) bfr[n] = *(const bf16x8*)(bBase + offB0 + n * 1024);
#pragma unroll
    for (int m = 0; m < 4; ++m) af[m] = *(const bf16x8*)(aBase + offA0 + m * 1024);
    STAGE_A(hs, sslot);
    __builtin_amdgcn_s_barrier();
    __builtin_amdgcn_s_setprio(1);
#pragma unroll
    for (int m = 0; m < 4; ++m)
#pragma unroll
      for (int n = 0; n < 4; ++n)
        acc[m][n] = __builtin_amdgcn_mfma_f32_16x16x32_bf16(af[m], bfr[n], acc[m][n], 0, 0, 0);
    __builtin_amdgcn_s_setprio(0);
    __builtin_amdgcn_s_barrier();

    // ---- phase 1: m-half 1 (B frags reused from regs) ----
#pragma unroll
    for (int m = 0; m < 4; ++m) af[m] = *(const bf16x8*)(aBase + offA0 + (m + 4) * 1024);
    STAGE_B(hs, sslot);
    __builtin_amdgcn_s_barrier();
    __builtin_amdgcn_s_setprio(1);
#pragma unroll
    for (int m = 0; m < 4; ++m)
#pragma unroll
      for (int n = 0; n < 4; ++n)
        acc[m + 4][n] = __builtin_amdgcn_mfma_f32_16x16x32_bf16(af[m], bfr[n], acc[m + 4][n], 0, 0, 0);
    __builtin_amdgcn_s_setprio(0);
    __builtin_amdgcn_s_barrier();
  }
#undef STAGE_A
#undef STAGE_B

  // ---- epilogue: C/D layout col = lane&15, row = (lane>>4)*4 + j (m89-verified) ----
  const int rowb = row0 + wr * 128 + fg * 4;
  const int colb = col0 + wc * 64 + fr;
  if (OUT_BF16) {
    unsigned short* Cp = (unsigned short*)Cv;
#pragma unroll
    for (int m = 0; m < 8; ++m)
#pragma unroll
      for (int n = 0; n < 4; ++n)
#pragma unroll
        for (int j = 0; j < 4; ++j)
          Cp[(size_t)(rowb + m * 16 + j) * N + (colb + n * 16)] = f2bf(acc[m][n][j]);
  } else {
    float* Cp = (float*)Cv;
#pragma unroll
    for (int m = 0; m < 8; ++m)
#pragma unroll
      for (int n = 0; n < 4; ++n)
#pragma unroll
        for (int j = 0; j < 4; ++j)
          Cp[(size_t)(rowb + m * 16 + j) * N + (colb + n * 16)] = acc[m][n][j];
  }
}

// ---------- launch ----------
extern "C" void kernel_launch(void* const* d_in, const int* in_sizes, int n_in,
                              void* d_out, int out_size, void* d_ws, size_t ws_size,
                              hipStream_t stream) {
  const int M = 4096, K = 7168, E = 2048;

  const float* x   = (const float*)d_in[0];  // [M,K]
  const float* wug = (const float*)d_in[1];  // [2E,K]
  const float* wd  = (const float*)d_in[2];  // [K,E]
  float* out = (float*)d_out;                // [M,K]

  // workspace layout (bytes)
  char* ws = (char*)d_ws;
  unsigned short* xb  = (unsigned short*)(ws);               //  58,720,256
  unsigned short* wub = (unsigned short*)(ws + 58720256);    //  58,720,256
  unsigned short* wdb = (unsigned short*)(ws + 117440512);   //  29,360,128
  unsigned short* ug  = (unsigned short*)(ws + 146800640);   //  33,554,432
  unsigned short* h   = (unsigned short*)(ws + 180355072);   //  16,777,216
  if (ws_size < 197132288) return;                           // need ~188 MiB

  // allow 128 KiB dynamic LDS (host-side calls, safe under graph capture)
  hipFuncSetAttribute((const void*)gemm_nt<7168, 4096, true>,
                      hipFuncAttributeMaxDynamicSharedMemorySize, 131072);
  hipFuncSetAttribute((const void*)gemm_nt<2048, 7168, false>,
                      hipFuncAttributeMaxDynamicSharedMemorySize, 131072);

  // 1) cast inputs to bf16
  cvt_f32_to_bf16<<<2048, 256, 0, stream>>>(x,   xb,  M * K / 4);
  cvt_f32_to_bf16<<<2048, 256, 0, stream>>>(wug, wub, 2 * E * K / 4);
  cvt_f32_to_bf16<<<1024, 256, 0, stream>>>(wd,  wdb, K * E / 4);

  // 2) ug = x @ w_up_gate^T   [4096, 4096] bf16  (16x16 = 256 blocks)
  gemm_nt<7168, 4096, true><<<256, 512, 131072, stream>>>(xb, wub, ug);

  // 3) h = silu(gate) * up    [4096, 2048] bf16
  swiglu_k<<<2048, 256, 0, stream>>>(ug, h, M * E / 8);

  // 4) out = h @ w_down^T     [4096, 7168] fp32  (16x28 = 448 blocks)
  gemm_nt<2048, 7168, false><<<448, 512, 131072, stream>>>(h, wdb, out);
}

// Round 3
// 388.930 us; speedup vs baseline: 1.6381x; 1.0475x over previous
//
#include <hip/hip_runtime.h>
#include <hip/hip_bf16.h>
#include <stdint.h>

// ---------- types ----------
typedef __attribute__((ext_vector_type(8))) short     bf16x8;  // MFMA A/B frag (4 VGPR)
typedef __attribute__((ext_vector_type(4))) float     f32x4;   // MFMA C/D frag

__device__ __forceinline__ unsigned short f2bf(float f) {
  unsigned int u = __float_as_uint(f);
  u += 0x7FFFu + ((u >> 16) & 1u);   // round-to-nearest-even
  return (unsigned short)(u >> 16);
}

__device__ __forceinline__ void async_cp16(const void* g, void* l) {
  __builtin_amdgcn_global_load_lds((const __attribute__((address_space(1))) void*)g,
                                   (__attribute__((address_space(3))) void*)l,
                                   16, 0, 0);
}

// ---------- fp32 -> bf16 conversion (memory-bound, vectorized) ----------
__global__ __launch_bounds__(256) void cvt_f32_to_bf16(const float* __restrict__ in,
                                                       unsigned short* __restrict__ out,
                                                       int n4) {
  int i = blockIdx.x * blockDim.x + threadIdx.x;
  const int stride = gridDim.x * blockDim.x;
  for (; i < n4; i += stride) {
    const float4 v = ((const float4*)in)[i];
    ushort4 o;
    o.x = f2bf(v.x); o.y = f2bf(v.y); o.z = f2bf(v.z); o.w = f2bf(v.w);
    ((ushort4*)out)[i] = o;
  }
}

// ---------- fp32 -> bf16 with gate/up row interleave ----------
// out row r (r in [0,4096)): g = r>>5, w = r&31;
//   src = g*16 + (w&15) + (w>=16 ? 2048 : 0)
// so each 32-row group = 16 gate rows + 16 up rows of the same e-block.
__global__ __launch_bounds__(256) void cvt_wug_perm(const float* __restrict__ in,
                                                    unsigned short* __restrict__ out,
                                                    int n4) {            // 4096*1792
  int i = blockIdx.x * blockDim.x + threadIdx.x;
  const int stride = gridDim.x * blockDim.x;
  for (; i < n4; i += stride) {
    const int r = i / 1792, c = i - r * 1792;
    const int g = r >> 5, w = r & 31;
    const int src = g * 16 + (w & 15) + ((w & 16) ? 2048 : 0);
    const float4 v = ((const float4*)in)[(size_t)src * 1792 + c];
    ushort4 o;
    o.x = f2bf(v.x); o.y = f2bf(v.y); o.z = f2bf(v.z); o.w = f2bf(v.w);
    ((ushort4*)out)[(size_t)r * 1792 + c] = o;
  }
}

// ---------- 256x256 deep-pipelined NT bf16 GEMM ----------
// C[m,n] = sum_k A[m,k]*B[n,k].  512 threads = 8 waves (2Mx4N), wave = 128x64 out.
// LDS: 4-slot ring at kstep (32-elem) granularity: slot = 16KB A + 16KB B = 128KiB.
// ONE barrier per kstep: vmcnt(8) (counted, never 0) folded before the end barrier.
// Ring-4 invariant: stage target slot (h+3)&3 was last READ in kstep h-1, i.e.
// before the barrier we just crossed -> no mid-kstep barriers needed.
// LDS line L (128B) holds rows 2L,2L+1; 16B-slot swizzle p = q ^ (L&7):
// read side conflict-free (bijective within 1KiB); staging pre-swizzles the
// per-lane GLOBAL source while LDS dest stays linear (m173 pattern).
// FUSE_SWIGLU: B rows pre-permuted (cvt_wug_perm) so frag n in {0,2} = gate,
// {1,3} = up of the same e-cols -> h = silu(g)*u in-lane, write [M, N/2] bf16.
template <int K, int N, bool FUSE_SWIGLU>
__global__ __launch_bounds__(512, 2) void gemm_nt(const unsigned short* __restrict__ A,
                                                  const unsigned short* __restrict__ B,
                                                  void* __restrict__ Cv) {
  extern __shared__ char sm[];   // 131072 bytes: [4 slots x 16KB A][4 slots x 16KB B]
  constexpr int nbx = N / 256;
  constexpr int nwg = (4096 / 256) * nbx;
  constexpr size_t K2 = (size_t)K * 2;

  // T1: bijective XCD swizzle (nwg % 8 == 0 for both GEMMs)
  const int bid = blockIdx.x;
  constexpr int q8 = nwg / 8;
  const int swz = (bid & 7) * q8 + (bid >> 3);
  const int bx = swz % nbx, by = swz / nbx;
  const int row0 = by * 256, col0 = bx * 256;

  const int tid = threadIdx.x, wave = tid >> 6, lane = tid & 63;
  const int wr = wave >> 2, wc = wave & 3;       // wave 2x4 grid
  const int fr = lane & 15, fg = lane >> 4;      // fragment row / k-group

  // ---- staging addresses (pre-swizzled global source, linear LDS dest) ----
  const int l3 = lane >> 3;                 // 0..7
  const int q  = (lane & 7) ^ l3;           // 0..7 involution
  const int qr = q >> 2;                    // row parity
  const int qc = (q & 3) * 16;              // byte offset within kstep's 64B row
  const char* gA[2]; const char* gB[2];
#pragma unroll
  for (int i = 0; i < 2; ++i) {
    const int L = i * 64 + wave * 8 + l3;   // LDS line 0..127
    gA[i] = (const char*)A + (size_t)(row0 + 2 * L + qr) * K2 + qc;
    gB[i] = (const char*)B + (size_t)(col0 + 2 * L + qr) * K2 + qc;
  }

  // ---- fragment read offsets (swizzled) ----
  const int rbA = wr * 128 + fr;
  const int offA0 = (rbA >> 1) * 128 + (((((rbA & 1) << 2) | fg) ^ ((rbA >> 1) & 7)) << 4);
  const int rbB = wc * 64 + fr;
  const int offB0 = (rbB >> 1) * 128 + (((((rbB & 1) << 2) | fg) ^ ((rbB >> 1) & 7)) << 4);

  f32x4 acc[8][4];
#pragma unroll
  for (int m = 0; m < 8; ++m)
#pragma unroll
    for (int n = 0; n < 4; ++n) acc[m][n] = (f32x4){0.f, 0.f, 0.f, 0.f};

  constexpr int nh = K / 32;    // ksteps

#define STAGE_A(h, slot) do {                                   \
    char* d_ = sm + (slot) * 16384 + wave * 1024;               \
    async_cp16(gA[0] + (size_t)(h) * 64, d_);                   \
    async_cp16(gA[1] + (size_t)(h) * 64, d_ + 8192);            \
  } while (0)
#define STAGE_B(h, slot) do {                                   \
    char* d_ = sm + 65536 + (slot) * 16384 + wave * 1024;       \
    async_cp16(gB[0] + (size_t)(h) * 64, d_);                   \
    async_cp16(gB[1] + (size_t)(h) * 64, d_ + 8192);            \
  } while (0)

  // prologue: stage ksteps 0,1,2 (12 loads in flight), make tile 0 ready
#pragma unroll
  for (int hp = 0; hp < 3; ++hp) { STAGE_A(hp, hp); STAGE_B(hp, hp); }
  asm volatile("s_waitcnt vmcnt(8)" ::: "memory");
  __builtin_amdgcn_s_barrier();

  // loop invariant at top: tile h resident in slot h&3; slots h+1,h+2 in flight
  for (int h = 0; h < nh; ++h) {
    const int slot = h & 3;
    const char* aBase = sm + slot * 16384;
    const char* bBase = sm + 65536 + slot * 16384;
    const int hs = (h + 3 < nh) ? h + 3 : nh - 1;   // clamped tail keeps vmcnt discipline
    const int sslot = (h + 3) & 3;                  // last read in kstep h-1 (pre-barrier)

    bf16x8 af[4], bfr[4];
#pragma unroll
    for (int n = 0; n < 4; ++n) bfr[n] = *(const bf16x8*)(bBase + offB0 + n * 1024);
#pragma unroll
    for (int m = 0; m < 4; ++m) af[m] = *(const bf16x8*)(aBase + offA0 + m * 1024);
    STAGE_A(hs, sslot);
    __builtin_amdgcn_s_setprio(1);
#pragma unroll
    for (int m = 0; m < 4; ++m)
#pragma unroll
      for (int n = 0; n < 4; ++n)
        acc[m][n] = __builtin_amdgcn_mfma_f32_16x16x32_bf16(af[m], bfr[n], acc[m][n], 0, 0, 0);
    __builtin_amdgcn_s_setprio(0);

#pragma unroll
    for (int m = 0; m < 4; ++m) af[m] = *(const bf16x8*)(aBase + offA0 + (m + 4) * 1024);
    STAGE_B(hs, sslot);
    __builtin_amdgcn_s_setprio(1);
#pragma unroll
    for (int m = 0; m < 4; ++m)
#pragma unroll
      for (int n = 0; n < 4; ++n)
        acc[m + 4][n] = __builtin_amdgcn_mfma_f32_16x16x32_bf16(af[m], bfr[n], acc[m + 4][n], 0, 0, 0);
    __builtin_amdgcn_s_setprio(0);

    // single sync point: own h+1 loads drained (12 outstanding -> 8), then barrier
    asm volatile("s_waitcnt vmcnt(8)" ::: "memory");
    __builtin_amdgcn_s_barrier();
  }
#undef STAGE_A
#undef STAGE_B

  // ---- epilogue: C/D layout col = lane&15, row = (lane>>4)*4 + j (m89-verified) ----
  const int rowb = row0 + wr * 128 + fg * 4;
  if (FUSE_SWIGLU) {
    // frag n in {0,2}: gate cols e = ecb + (n/2)*16; n in {1,3}: up, same e
    unsigned short* Hp = (unsigned short*)Cv;
    const int ecb = ((col0 + wc * 64) >> 1) + fr;
#pragma unroll
    for (int m = 0; m < 8; ++m)
#pragma unroll
      for (int p = 0; p < 2; ++p)
#pragma unroll
        for (int j = 0; j < 4; ++j) {
          const float gv = acc[m][2 * p][j];
          const float uv = acc[m][2 * p + 1][j];
          const float s  = gv / (1.0f + __expf(-gv));
          Hp[(size_t)(rowb + m * 16 + j) * (N / 2) + (ecb + p * 16)] = f2bf(s * uv);
        }
  } else {
    float* Cp = (float*)Cv;
    const int colb = col0 + wc * 64 + fr;
#pragma unroll
    for (int m = 0; m < 8; ++m)
#pragma unroll
      for (int n = 0; n < 4; ++n)
#pragma unroll
        for (int j = 0; j < 4; ++j)
          Cp[(size_t)(rowb + m * 16 + j) * N + (colb + n * 16)] = acc[m][n][j];
  }
}

// ---------- launch ----------
extern "C" void kernel_launch(void* const* d_in, const int* in_sizes, int n_in,
                              void* d_out, int out_size, void* d_ws, size_t ws_size,
                              hipStream_t stream) {
  const int M = 4096, K = 7168, E = 2048;

  const float* x   = (const float*)d_in[0];  // [M,K]
  const float* wug = (const float*)d_in[1];  // [2E,K]
  const float* wd  = (const float*)d_in[2];  // [K,E]
  float* out = (float*)d_out;                // [M,K]

  // workspace layout (bytes)
  char* ws = (char*)d_ws;
  unsigned short* xb  = (unsigned short*)(ws);               //  58,720,256
  unsigned short* wub = (unsigned short*)(ws + 58720256);    //  58,720,256 (permuted)
  unsigned short* wdb = (unsigned short*)(ws + 117440512);   //  29,360,128
  unsigned short* h   = (unsigned short*)(ws + 146800640);   //  16,777,216
  if (ws_size < 163577856) return;                           // need ~156 MiB

  // allow 128 KiB dynamic LDS (host-side calls, safe under graph capture)
  hipFuncSetAttribute((const void*)gemm_nt<7168, 4096, true>,
                      hipFuncAttributeMaxDynamicSharedMemorySize, 131072);
  hipFuncSetAttribute((const void*)gemm_nt<2048, 7168, false>,
                      hipFuncAttributeMaxDynamicSharedMemorySize, 131072);

  // 1) cast inputs to bf16 (wug with gate/up interleave permutation)
  cvt_f32_to_bf16<<<2048, 256, 0, stream>>>(x,   xb,  M * K / 4);
  cvt_wug_perm  <<<2048, 256, 0, stream>>>(wug, wub, 2 * E * K / 4);
  cvt_f32_to_bf16<<<1024, 256, 0, stream>>>(wd,  wdb, K * E / 4);

  // 2) h = swiglu(x @ w_up_gate^T) fused   [4096, 2048] bf16  (16x16 = 256 blocks)
  gemm_nt<7168, 4096, true><<<256, 512, 131072, stream>>>(xb, wub, h);

  // 3) out = h @ w_down^T     [4096, 7168] fp32  (16x28 = 448 blocks)
  gemm_nt<2048, 7168, false><<<448, 512, 131072, stream>>>(h, wdb, out);
}